// Round 2
// baseline (52.798 us; speedup 1.0000x reference)
//
#include <hip/hip_runtime.h>

// Problem constants (from reference)
static constexpr int      B_TOTAL  = 4194304;
static constexpr unsigned POS_MASK = 0xD2u; // classes 1,4,6,7 POSITIVE: bits 1,4,6,7
static constexpr int      BLOCKS   = 2048;
static constexpr int      THREADS  = 256;

__device__ __forceinline__ float fast_exp2(float x) {
#if __has_builtin(__builtin_amdgcn_exp2f)
    return __builtin_amdgcn_exp2f(x);
#else
    return exp2f(x);
#endif
}

__device__ __forceinline__ float fast_log2(float x) {
#if __has_builtin(__builtin_amdgcn_logf)
    return __builtin_amdgcn_logf(x);
#else
    return log2f(x);
#endif
}

// Weighted CE for one 8-class sample held in two float4s.
// Polarity of argmax computed WITHOUT the argmax index:
//   mp = max over positive classes {1,4,6,7}, mn = max over negative {0,2,3,5}
//   predicted polarity = (mp > mn). Exact cross-group ties (measure-zero on
//   random float data) may differ from first-occurrence argmax; effect on the
//   mean is ~1e-7, far below tolerance.
__device__ __forceinline__ float wce8(const float4 lo, const float4 hi,
                                      const int lbl, const unsigned lblPol) {
    constexpr float LOG2E = 1.4426950408889634f;
    constexpr float LN2   = 0.6931471805599453f;

    const float mp = fmaxf(fmaxf(lo.y, hi.x), fmaxf(hi.z, hi.w)); // x1,x4,x6,x7
    const float mn = fmaxf(fmaxf(lo.x, lo.z), fmaxf(lo.w, hi.y)); // x0,x2,x3,x5
    const float m  = fmaxf(mp, mn);

    const float c = -m * LOG2E;
    float s;
    s  = fast_exp2(fmaf(lo.x, LOG2E, c));
    s += fast_exp2(fmaf(lo.y, LOG2E, c));
    s += fast_exp2(fmaf(lo.z, LOG2E, c));
    s += fast_exp2(fmaf(lo.w, LOG2E, c));
    s += fast_exp2(fmaf(hi.x, LOG2E, c));
    s += fast_exp2(fmaf(hi.y, LOG2E, c));
    s += fast_exp2(fmaf(hi.z, LOG2E, c));
    s += fast_exp2(fmaf(hi.w, LOG2E, c));

    // x[lbl] via select chain (compile-time indices only — no scratch)
    float xl = lo.x;
    xl = (lbl == 1) ? lo.y : xl;
    xl = (lbl == 2) ? lo.z : xl;
    xl = (lbl == 3) ? lo.w : xl;
    xl = (lbl == 4) ? hi.x : xl;
    xl = (lbl == 5) ? hi.y : xl;
    xl = (lbl == 6) ? hi.z : xl;
    xl = (lbl == 7) ? hi.w : xl;

    const unsigned predPol = (mp > mn) ? 1u : 0u;
    const float w = (lblPol != predPol) ? 1.5f : 1.0f;

    // ce = m + ln2*log2(s) - xl
    return (fmaf(LN2, fast_log2(s), m) - xl) * w;
}

__device__ __forceinline__ float block_reduce(float acc) {
    #pragma unroll
    for (int off = 32; off > 0; off >>= 1)
        acc += __shfl_down(acc, off);
    __shared__ float smem[THREADS / 64];
    const int wave = threadIdx.x >> 6;
    if ((threadIdx.x & 63) == 0) smem[wave] = acc;
    __syncthreads();
    float t = 0.0f;
    if (threadIdx.x == 0) {
        #pragma unroll
        for (int w = 0; w < THREADS / 64; ++w) t += smem[w];
    }
    return t; // valid only on thread 0
}

__global__ __launch_bounds__(THREADS) void pcce_main(
    const float* __restrict__ a, const float* __restrict__ v,
    const int* __restrict__ y, float* __restrict__ partials, const int n)
{
    const float4* __restrict__ a4 = reinterpret_cast<const float4*>(a);
    const float4* __restrict__ v4 = reinterpret_cast<const float4*>(v);
    const int tid    = blockIdx.x * blockDim.x + threadIdx.x;
    const int stride = gridDim.x * blockDim.x;

    float acc = 0.0f;
    int i = tid;
    const int iters = n / stride; // exact 8 with default launch

    #pragma unroll 2
    for (int it = 0; it < iters; ++it) {
        const int lbl = y[i];
        const float4 alo = a4[2 * i], ahi = a4[2 * i + 1];
        const float4 vlo = v4[2 * i], vhi = v4[2 * i + 1];
        const unsigned lp = (POS_MASK >> lbl) & 1u;
        acc += wce8(alo, ahi, lbl, lp);
        acc += wce8(vlo, vhi, lbl, lp);
        i += stride;
    }
    for (; i < n; i += stride) { // tail (empty with default launch)
        const int lbl = y[i];
        const float4 alo = a4[2 * i], ahi = a4[2 * i + 1];
        const float4 vlo = v4[2 * i], vhi = v4[2 * i + 1];
        const unsigned lp = (POS_MASK >> lbl) & 1u;
        acc += wce8(alo, ahi, lbl, lp);
        acc += wce8(vlo, vhi, lbl, lp);
    }

    const float t = block_reduce(acc);
    if (threadIdx.x == 0) partials[blockIdx.x] = t;
}

// Fallback path (no-ws): atomic accumulate directly into out (pre-zeroed).
__global__ __launch_bounds__(THREADS) void pcce_main_atomic(
    const float* __restrict__ a, const float* __restrict__ v,
    const int* __restrict__ y, float* __restrict__ out, const int n)
{
    const float4* __restrict__ a4 = reinterpret_cast<const float4*>(a);
    const float4* __restrict__ v4 = reinterpret_cast<const float4*>(v);
    const int tid    = blockIdx.x * blockDim.x + threadIdx.x;
    const int stride = gridDim.x * blockDim.x;

    float acc = 0.0f;
    for (int i = tid; i < n; i += stride) {
        const int lbl = y[i];
        const float4 alo = a4[2 * i], ahi = a4[2 * i + 1];
        const float4 vlo = v4[2 * i], vhi = v4[2 * i + 1];
        const unsigned lp = (POS_MASK >> lbl) & 1u;
        acc += wce8(alo, ahi, lbl, lp);
        acc += wce8(vlo, vhi, lbl, lp);
    }

    const float t = block_reduce(acc);
    if (threadIdx.x == 0) atomicAdd(out, t * (1.0f / (float)B_TOTAL));
}

__global__ __launch_bounds__(256) void pcce_reduce(
    const float* __restrict__ partials, const int nb, float* __restrict__ out)
{
    float acc = 0.0f;
    for (int i = threadIdx.x; i < nb; i += 256) acc += partials[i];
    #pragma unroll
    for (int off = 32; off > 0; off >>= 1)
        acc += __shfl_down(acc, off);
    __shared__ float smem[4];
    if ((threadIdx.x & 63) == 0) smem[threadIdx.x >> 6] = acc;
    __syncthreads();
    if (threadIdx.x == 0)
        out[0] = (smem[0] + smem[1] + smem[2] + smem[3]) * (1.0f / (float)B_TOTAL);
}

extern "C" void kernel_launch(void* const* d_in, const int* in_sizes, int n_in,
                              void* d_out, int out_size, void* d_ws, size_t ws_size,
                              hipStream_t stream) {
    const float* a = (const float*)d_in[0];
    const float* v = (const float*)d_in[1];
    const int*   y = (const int*)d_in[2];
    float* out = (float*)d_out;
    const int n = in_sizes[2]; // B

    if (ws_size >= (size_t)BLOCKS * sizeof(float)) {
        float* partials = (float*)d_ws;
        pcce_main<<<BLOCKS, THREADS, 0, stream>>>(a, v, y, partials, n);
        pcce_reduce<<<1, 256, 0, stream>>>(partials, BLOCKS, out);
    } else {
        hipMemsetAsync(out, 0, sizeof(float), stream);
        pcce_main_atomic<<<BLOCKS, THREADS, 0, stream>>>(a, v, y, out, n);
    }
}